// Round 1
// baseline (2976.842 us; speedup 1.0000x reference)
//
#include <hip/hip_runtime.h>
#include <math.h>

constexpr int Bn = 8, NZ = 16, Ln = 512;
constexpr int E = 256, DM = 512, NH = 16, HD = 32;
constexpr int FF = 1024, NL = 8, E1D = 32, PDIM = 64, PMAX = 24;
constexpr int ROWS = Bn * Ln;                       // 4096
constexpr float QSCALE = 0.04419417382415922f;      // 1/sqrt(512)

// ---------------------------------------------------------------------------
// embed_x MLP + e_aa gather (writes h and um[:,256:288])
// ---------------------------------------------------------------------------
__global__ __launch_bounds__(256) void embed_kernel(
    const float* __restrict__ z, const float* __restrict__ x,
    const float* __restrict__ aa,
    const float* __restrict__ w1, const float* __restrict__ b1,
    const float* __restrict__ w2, const float* __restrict__ b2,
    float* __restrict__ h, float* __restrict__ um)
{
  int row = blockIdx.x;
  int b = row >> 9, l = row & (Ln - 1);
  int t = threadIdx.x;
  __shared__ float zs[NZ];
  __shared__ float ts[E];
  __shared__ int am_s;
  if (t < NZ) zs[t] = z[((size_t)b * NZ + t) * Ln + l];
  if (t == 0) {
    const float* xp = x + (size_t)b * 20 * Ln + l;
    int am = 0; float bv = xp[0];
    for (int c = 1; c < 20; ++c) { float vv = xp[(size_t)c * Ln]; if (vv > bv) { bv = vv; am = c; } }
    am_s = am;
  }
  __syncthreads();
  float a1 = b1[t];
  #pragma unroll
  for (int nz = 0; nz < NZ; ++nz) a1 += zs[nz] * w1[nz * E + t];
  ts[t] = fmaxf(a1, 0.f);
  if (t < E1D) um[(size_t)row * (E + E1D) + E + t] = aa[am_s * E1D + t];
  __syncthreads();
  float a2 = b2[t];
  for (int kk = 0; kk < E; ++kk) a2 += ts[kk] * w2[kk * E + t];
  h[(size_t)row * E + t] = a2;
}

// ---------------------------------------------------------------------------
// pairwise-bias collapse: bias only depends on clip(m-l,±24) -> 49 bins
// bias49[i][h][bin] = sum_p pos_table[bin][p] * W2d[i][p][h] + b2d[i][h]
// ---------------------------------------------------------------------------
__global__ __launch_bounds__(256) void bias_kernel(
    const float* __restrict__ pos, const float* __restrict__ W2d,
    const float* __restrict__ b2d, float* __restrict__ bias49)
{
  int layer = blockIdx.x;
  for (int idx = threadIdx.x; idx < NH * 49; idx += 256) {
    int hh = idx / 49, bin = idx % 49;
    float acc = b2d[layer * NH + hh];
    for (int p = 0; p < PDIM; ++p)
      acc += pos[bin * PDIM + p] * W2d[((size_t)layer * PDIM + p) * NH + hh];
    bias49[(size_t)layer * NH * 49 + hh * 49 + bin] = acc;
  }
}

// ---------------------------------------------------------------------------
// generic fp32 tiled GEMM: C = act(A@B * scale + bias) + resid
// BM=BN=64, BK=16, 256 threads, 4x4 micro-tile
// ---------------------------------------------------------------------------
template<bool RELU, bool BIAS, bool RESID>
__global__ __launch_bounds__(256) void gemm64(
    const float* __restrict__ A, const float* __restrict__ B,
    const float* __restrict__ bias, const float* __restrict__ resid,
    float* __restrict__ C, int N, int K, float scale)
{
  __shared__ __align__(16) float As[16][64];   // As[k][m]
  __shared__ __align__(16) float Bs[16][68];   // Bs[k][n], pad 68 (272B, 16B-aligned rows)
  const int tid = threadIdx.x;
  const int tx = tid & 15, ty = tid >> 4;
  const int m0 = blockIdx.y * 64, n0 = blockIdx.x * 64;
  const int arow = tid >> 2, acol = (tid & 3) * 4;
  const int brow = tid >> 6, bcol = tid & 63;
  float acc[4][4] = {};
  for (int kb = 0; kb < K; kb += 16) {
    __syncthreads();
    float4 av = *(const float4*)(A + (size_t)(m0 + arow) * K + kb + acol);
    As[acol + 0][arow] = av.x; As[acol + 1][arow] = av.y;
    As[acol + 2][arow] = av.z; As[acol + 3][arow] = av.w;
    #pragma unroll
    for (int kk = 0; kk < 4; ++kk)
      Bs[brow + kk * 4][bcol] = B[(size_t)(kb + brow + kk * 4) * N + n0 + bcol];
    __syncthreads();
    #pragma unroll
    for (int k = 0; k < 16; ++k) {
      float4 a = *(const float4*)&As[k][4 * ty];
      float4 b = *(const float4*)&Bs[k][4 * tx];
      float av4[4] = {a.x, a.y, a.z, a.w};
      float bv4[4] = {b.x, b.y, b.z, b.w};
      #pragma unroll
      for (int ii = 0; ii < 4; ++ii)
        #pragma unroll
        for (int jj = 0; jj < 4; ++jj)
          acc[ii][jj] += av4[ii] * bv4[jj];
    }
  }
  #pragma unroll
  for (int ii = 0; ii < 4; ++ii) {
    size_t row = (size_t)m0 + 4 * ty + ii;
    int col = n0 + 4 * tx;
    float4 vv;
    vv.x = acc[ii][0] * scale; vv.y = acc[ii][1] * scale;
    vv.z = acc[ii][2] * scale; vv.w = acc[ii][3] * scale;
    if (BIAS) {
      float4 bb = *(const float4*)(bias + col);
      vv.x += bb.x; vv.y += bb.y; vv.z += bb.z; vv.w += bb.w;
    }
    if (RELU) {
      vv.x = fmaxf(vv.x, 0.f); vv.y = fmaxf(vv.y, 0.f);
      vv.z = fmaxf(vv.z, 0.f); vv.w = fmaxf(vv.w, 0.f);
    }
    if (RESID) {
      float4 rr = *(const float4*)(resid + row * N + col);
      vv.x += rr.x; vv.y += rr.y; vv.z += rr.z; vv.w += rr.w;
    }
    *(float4*)(C + row * N + col) = vv;
  }
}

// ---------------------------------------------------------------------------
// fused flash attention: per (query-tile 64, b*h) block; K/V in LDS,
// online softmax, never materializes S globally. Adds 49-bin bias.
// ---------------------------------------------------------------------------
__global__ __launch_bounds__(256) void attn_kernel(
    const float* __restrict__ q, const float* __restrict__ k,
    const float* __restrict__ v, const float* __restrict__ bias49,
    float* __restrict__ o)
{
  const int it = blockIdx.x;           // 0..7 query tile
  const int bh = blockIdx.y;           // 0..127
  const int b = bh >> 4, hh = bh & 15;
  const int tid = threadIdx.x;
  const int tx = tid & 15, ty = tid >> 4;
  const int i0 = it * 64;

  __shared__ __align__(16) float Qt[32][68];   // [d][i]
  __shared__ __align__(16) float Kt[32][68];   // [d][j]
  __shared__ __align__(16) float Vs[64][36];   // [j][d]
  __shared__ __align__(16) float Ss[64][76];   // [i][j]
  __shared__ float m_s[64], l_s[64], al_s[64];
  __shared__ float red[64][4];
  __shared__ float bsh[49];

  if (tid < 49) bsh[tid] = bias49[hh * 49 + tid];
  if (tid < 64) { m_s[tid] = -1e30f; l_s[tid] = 0.f; }
  const size_t base = ((size_t)b * Ln) * (NH * HD) + (size_t)hh * HD;
  #pragma unroll
  for (int r2 = 0; r2 < 8; ++r2) {
    int idx = tid + r2 * 256;
    int i = idx >> 5, d = idx & 31;
    Qt[d][i] = q[base + (size_t)(i0 + i) * (NH * HD) + d];
  }
  float acc[4][2] = {};
  const int row = tid >> 2, seg = tid & 3;

  for (int jt = 0; jt < 8; ++jt) {
    const int j0 = jt * 64;
    __syncthreads();                       // prior PV reads done; Qt/init visible
    #pragma unroll
    for (int r2 = 0; r2 < 8; ++r2) {
      int idx = tid + r2 * 256;
      int i = idx >> 5, d = idx & 31;
      Kt[d][i] = k[base + (size_t)(j0 + i) * (NH * HD) + d];
      Vs[i][d] = v[base + (size_t)(j0 + i) * (NH * HD) + d];
    }
    __syncthreads();
    // ---- S tile = Q K^T + bias ----
    float s[4][4];
    #pragma unroll
    for (int ii = 0; ii < 4; ++ii)
      #pragma unroll
      for (int jj = 0; jj < 4; ++jj) {
        int rel = (j0 + 4 * tx + jj) - (i0 + 4 * ty + ii);
        rel = rel < -PMAX ? -PMAX : (rel > PMAX ? PMAX : rel);
        s[ii][jj] = bsh[rel + PMAX];
      }
    #pragma unroll
    for (int d = 0; d < 32; ++d) {
      float4 a = *(const float4*)&Qt[d][4 * ty];
      float4 bq = *(const float4*)&Kt[d][4 * tx];
      float av4[4] = {a.x, a.y, a.z, a.w};
      float bv4[4] = {bq.x, bq.y, bq.z, bq.w};
      #pragma unroll
      for (int ii = 0; ii < 4; ++ii)
        #pragma unroll
        for (int jj = 0; jj < 4; ++jj)
          s[ii][jj] += av4[ii] * bv4[jj];
    }
    #pragma unroll
    for (int ii = 0; ii < 4; ++ii)
      *(float4*)&Ss[4 * ty + ii][4 * tx] = make_float4(s[ii][0], s[ii][1], s[ii][2], s[ii][3]);
    __syncthreads();
    // ---- online softmax update (4 threads per row, 16 cols each) ----
    float mx = -1e30f;
    #pragma unroll
    for (int c = 0; c < 16; ++c) mx = fmaxf(mx, Ss[row][seg * 16 + c]);
    red[row][seg] = mx;
    __syncthreads();
    float tmax = fmaxf(fmaxf(red[row][0], red[row][1]), fmaxf(red[row][2], red[row][3]));
    float mold = m_s[row];
    float mnew = fmaxf(mold, tmax);
    float ps = 0.f;
    #pragma unroll
    for (int c = 0; c < 16; ++c) {
      float p = __expf(Ss[row][seg * 16 + c] - mnew);
      Ss[row][seg * 16 + c] = p;
      ps += p;
    }
    __syncthreads();                 // red max reads + m_s reads complete
    red[row][seg] = ps;
    __syncthreads();
    if (seg == 0) {
      float al = __expf(mold - mnew);
      l_s[row] = l_s[row] * al + (red[row][0] + red[row][1] + red[row][2] + red[row][3]);
      m_s[row] = mnew;
      al_s[row] = al;
    }
    __syncthreads();
    // ---- O update: O = O*alpha + P @ V ----
    #pragma unroll
    for (int ii = 0; ii < 4; ++ii) {
      float al = al_s[4 * ty + ii];
      acc[ii][0] *= al; acc[ii][1] *= al;
    }
    for (int j4 = 0; j4 < 64; j4 += 4) {
      float2 vv0 = *(const float2*)&Vs[j4 + 0][2 * tx];
      float2 vv1 = *(const float2*)&Vs[j4 + 1][2 * tx];
      float2 vv2 = *(const float2*)&Vs[j4 + 2][2 * tx];
      float2 vv3 = *(const float2*)&Vs[j4 + 3][2 * tx];
      #pragma unroll
      for (int ii = 0; ii < 4; ++ii) {
        float4 p4 = *(const float4*)&Ss[4 * ty + ii][j4];
        acc[ii][0] += p4.x * vv0.x + p4.y * vv1.x + p4.z * vv2.x + p4.w * vv3.x;
        acc[ii][1] += p4.x * vv0.y + p4.y * vv1.y + p4.z * vv2.y + p4.w * vv3.y;
      }
    }
  }
  #pragma unroll
  for (int ii = 0; ii < 4; ++ii) {
    float linv = 1.f / l_s[4 * ty + ii];
    float2 ov;
    ov.x = acc[ii][0] * linv; ov.y = acc[ii][1] * linv;
    *(float2*)&o[base + (size_t)(i0 + 4 * ty + ii) * (NH * HD) + 2 * tx] = ov;
  }
}

// ---------------------------------------------------------------------------
// LayerNorm over E=256 (one block per row); optionally mirrors into um[:, :256]
// ---------------------------------------------------------------------------
__global__ __launch_bounds__(256) void ln_kernel(
    const float* __restrict__ xin, const float* __restrict__ g,
    const float* __restrict__ be, float* __restrict__ hout,
    float* __restrict__ umout)
{
  int row = blockIdx.x, t = threadIdx.x;
  float v = xin[(size_t)row * E + t];
  float s = v;
  #pragma unroll
  for (int off = 32; off > 0; off >>= 1) s += __shfl_down(s, off, 64);
  __shared__ float ws4[4];
  __shared__ float mbc, rbc;
  if ((t & 63) == 0) ws4[t >> 6] = s;
  __syncthreads();
  if (t == 0) mbc = (ws4[0] + ws4[1] + ws4[2] + ws4[3]) * (1.f / E);
  __syncthreads();
  float m = mbc;
  float d = v - m;
  float s2 = d * d;
  #pragma unroll
  for (int off = 32; off > 0; off >>= 1) s2 += __shfl_down(s2, off, 64);
  if ((t & 63) == 0) ws4[t >> 6] = s2;
  __syncthreads();
  if (t == 0) rbc = rsqrtf((ws4[0] + ws4[1] + ws4[2] + ws4[3]) * (1.f / E) + 1e-5f);
  __syncthreads();
  float y = d * rbc * g[t] + be[t];
  hout[(size_t)row * E + t] = y;
  if (umout) umout[(size_t)row * (E + E1D) + t] = y;
}

// ---------------------------------------------------------------------------
// head: r = t1 @ m3_w2 + m3_b2  (N=3, block-per-row reduction)
// ---------------------------------------------------------------------------
__global__ __launch_bounds__(256) void final_r_kernel(
    const float* __restrict__ t1, const float* __restrict__ w2,
    const float* __restrict__ b2, float* __restrict__ r)
{
  int row = blockIdx.x, t = threadIdx.x;
  float xv = t1[(size_t)row * E + t];
  float p0 = xv * w2[t * 3 + 0];
  float p1 = xv * w2[t * 3 + 1];
  float p2 = xv * w2[t * 3 + 2];
  #pragma unroll
  for (int off = 32; off > 0; off >>= 1) {
    p0 += __shfl_down(p0, off, 64);
    p1 += __shfl_down(p1, off, 64);
    p2 += __shfl_down(p2, off, 64);
  }
  __shared__ float red[4][3];
  if ((t & 63) == 0) { int w = t >> 6; red[w][0] = p0; red[w][1] = p1; red[w][2] = p2; }
  __syncthreads();
  if (t < 3)
    r[(size_t)row * 3 + t] = red[0][t] + red[1][t] + red[2][t] + red[3][t] + b2[t];
}

// ---------------------------------------------------------------------------
// pairwise distance map
// ---------------------------------------------------------------------------
__global__ __launch_bounds__(512) void dist_kernel(
    const float* __restrict__ r, float* __restrict__ out)
{
  int bi = blockIdx.x;            // b*512 + i
  int j = threadIdx.x;            // 0..511
  int b = bi >> 9;
  float x0 = r[(size_t)bi * 3 + 0];
  float y0 = r[(size_t)bi * 3 + 1];
  float z0 = r[(size_t)bi * 3 + 2];
  const float* rj = r + ((size_t)b * Ln + j) * 3;
  float dx = rj[0] - x0, dy = rj[1] - y0, dz = rj[2] - z0;
  out[(size_t)bi * Ln + j] = sqrtf(dx * dx + dy * dy + dz * dz + 1e-12f);
}

// ---------------------------------------------------------------------------
extern "C" void kernel_launch(void* const* d_in, const int* in_sizes, int n_in,
                              void* d_out, int out_size, void* d_ws, size_t ws_size,
                              hipStream_t stream)
{
  const float* z     = (const float*)d_in[0];
  const float* x     = (const float*)d_in[1];
  const float* pos   = (const float*)d_in[2];
  const float* aa    = (const float*)d_in[3];
  const float* ex_w1 = (const float*)d_in[4];
  const float* ex_b1 = (const float*)d_in[5];
  const float* ex_w2 = (const float*)d_in[6];
  const float* ex_b2 = (const float*)d_in[7];
  const float* Wq    = (const float*)d_in[8];
  const float* Wk    = (const float*)d_in[9];
  const float* Wv    = (const float*)d_in[10];
  const float* Wo    = (const float*)d_in[11];
  const float* bo    = (const float*)d_in[12];
  const float* W2d   = (const float*)d_in[13];
  const float* b2d   = (const float*)d_in[14];
  const float* W1    = (const float*)d_in[15];
  const float* b1    = (const float*)d_in[16];
  const float* W2    = (const float*)d_in[17];
  const float* b2    = (const float*)d_in[18];
  const float* g1    = (const float*)d_in[19];
  const float* be1   = (const float*)d_in[20];
  const float* g2    = (const float*)d_in[21];
  const float* be2   = (const float*)d_in[22];
  const float* m3w1  = (const float*)d_in[23];
  const float* m3b1  = (const float*)d_in[24];
  const float* m3w2  = (const float*)d_in[25];
  const float* m3b2  = (const float*)d_in[26];

  float* ws   = (float*)d_ws;
  float* h    = ws;                       // 4096*256
  float* um   = h    + (size_t)ROWS * E;  // 4096*288
  float* qb   = um   + (size_t)ROWS * (E + E1D);
  float* kb   = qb   + (size_t)ROWS * DM;
  float* vb   = kb   + (size_t)ROWS * DM;
  float* ob   = vb   + (size_t)ROWS * DM;
  float* tmp  = ob   + (size_t)ROWS * DM;
  float* t1   = tmp  + (size_t)ROWS * E;
  float* bias49 = t1 + (size_t)ROWS * FF;
  float* r    = bias49 + (size_t)NL * NH * 49;
  // total ~15.9M floats (~64 MB)

  embed_kernel<<<ROWS, 256, 0, stream>>>(z, x, aa, ex_w1, ex_b1, ex_w2, ex_b2, h, um);
  bias_kernel<<<NL, 256, 0, stream>>>(pos, W2d, b2d, bias49);

  for (int i = 0; i < NL; ++i) {
    gemm64<false,false,false><<<dim3(DM/64, ROWS/64), 256, 0, stream>>>(
        h, Wq + (size_t)i * E * DM, nullptr, nullptr, qb, DM, E, QSCALE);
    gemm64<false,false,false><<<dim3(DM/64, ROWS/64), 256, 0, stream>>>(
        h, Wk + (size_t)i * E * DM, nullptr, nullptr, kb, DM, E, 1.f);
    gemm64<false,false,false><<<dim3(DM/64, ROWS/64), 256, 0, stream>>>(
        h, Wv + (size_t)i * E * DM, nullptr, nullptr, vb, DM, E, 1.f);
    attn_kernel<<<dim3(Ln/64, Bn*NH), 256, 0, stream>>>(
        qb, kb, vb, bias49 + (size_t)i * NH * 49, ob);
    gemm64<false,true,true><<<dim3(E/64, ROWS/64), 256, 0, stream>>>(
        ob, Wo + (size_t)i * DM * E, bo + (size_t)i * E, h, tmp, E, DM, 1.f);
    ln_kernel<<<ROWS, 256, 0, stream>>>(tmp, g1 + (size_t)i * E, be1 + (size_t)i * E, h, um);
    gemm64<true,true,false><<<dim3(FF/64, ROWS/64), 256, 0, stream>>>(
        um, W1 + (size_t)i * (E + E1D) * FF, b1 + (size_t)i * FF, nullptr, t1, FF, E + E1D, 1.f);
    gemm64<false,true,true><<<dim3(E/64, ROWS/64), 256, 0, stream>>>(
        t1, W2 + (size_t)i * FF * E, b2 + (size_t)i * E, h, tmp, E, FF, 1.f);
    ln_kernel<<<ROWS, 256, 0, stream>>>(tmp, g2 + (size_t)i * E, be2 + (size_t)i * E, h, nullptr);
  }

  gemm64<true,true,false><<<dim3(E/64, ROWS/64), 256, 0, stream>>>(
      h, m3w1, m3b1, nullptr, t1, E, E, 1.f);
  final_r_kernel<<<ROWS, 256, 0, stream>>>(t1, m3w2, m3b2, r);
  dist_kernel<<<ROWS, 512, 0, stream>>>(r, (float*)d_out);
}

// Round 3
// 1448.027 us; speedup vs baseline: 2.0558x; 2.0558x over previous
//
#include <hip/hip_runtime.h>
#include <math.h>

constexpr int Bn = 8, NZ = 16, Ln = 512;
constexpr int E = 256, DM = 512, NH = 16, HD = 32;
constexpr int FF = 1024, NL = 8, E1D = 32, PDIM = 64, PMAX = 24;
constexpr int ROWS = Bn * Ln;                       // 4096
constexpr float QSCALE = 0.04419417382415922f;      // 1/sqrt(512)

typedef __attribute__((ext_vector_type(8))) short bf16x8;
typedef __attribute__((ext_vector_type(4))) float floatx4;

__device__ inline unsigned short f2b(float f) {
  union { float f; unsigned u; } v; v.f = f;
  unsigned r = (v.u + 0x7FFF + ((v.u >> 16) & 1)) >> 16;
  return (unsigned short)r;
}
__device__ inline float b2f(unsigned short u) {
  union { unsigned u; float f; } v; v.u = ((unsigned)u) << 16; return v.f;
}

// ---------------------------------------------------------------------------
// fp32 [l][R][C] -> bf16 [l][C][R] tiled transpose+convert (weights, per call)
// ---------------------------------------------------------------------------
__global__ __launch_bounds__(256) void transpose_bf16(
    const float* __restrict__ src, unsigned short* __restrict__ dst,
    int R, int C, size_t sls, size_t dls)
{
  __shared__ float t[32][33];
  int l = blockIdx.z;
  int c0 = blockIdx.x * 32, r0 = blockIdx.y * 32;
  int tx = threadIdx.x & 31, ty = threadIdx.x >> 5;   // 32 x 8
  const float* s = src + (size_t)l * sls;
  unsigned short* d = dst + (size_t)l * dls;
  #pragma unroll
  for (int i = 0; i < 4; ++i)
    t[ty + i * 8][tx] = s[(size_t)(r0 + ty + i * 8) * C + c0 + tx];
  __syncthreads();
  #pragma unroll
  for (int i = 0; i < 4; ++i)
    d[(size_t)(c0 + ty + i * 8) * R + r0 + tx] = f2b(t[tx][ty + i * 8]);
}

// ---------------------------------------------------------------------------
// embed_x MLP + e_aa gather: writes h (fp32), hb (bf16), umb aa-cols (bf16)
// ---------------------------------------------------------------------------
__global__ __launch_bounds__(256) void embed_kernel(
    const float* __restrict__ z, const float* __restrict__ x,
    const float* __restrict__ aa,
    const float* __restrict__ w1, const float* __restrict__ b1,
    const float* __restrict__ w2, const float* __restrict__ b2,
    float* __restrict__ h, unsigned short* __restrict__ hb,
    unsigned short* __restrict__ umb)
{
  int row = blockIdx.x;
  int b = row >> 9, l = row & (Ln - 1);
  int t = threadIdx.x;
  __shared__ float zs[NZ];
  __shared__ float ts[E];
  __shared__ int am_s;
  if (t < NZ) zs[t] = z[((size_t)b * NZ + t) * Ln + l];
  if (t == 0) {
    const float* xp = x + (size_t)b * 20 * Ln + l;
    int am = 0; float bv = xp[0];
    for (int c = 1; c < 20; ++c) { float vv = xp[(size_t)c * Ln]; if (vv > bv) { bv = vv; am = c; } }
    am_s = am;
  }
  __syncthreads();
  float a1 = b1[t];
  #pragma unroll
  for (int nz = 0; nz < NZ; ++nz) a1 += zs[nz] * w1[nz * E + t];
  ts[t] = fmaxf(a1, 0.f);
  if (t < E1D) umb[(size_t)row * (E + E1D) + E + t] = f2b(aa[am_s * E1D + t]);
  __syncthreads();
  float a2 = b2[t];
  for (int kk = 0; kk < E; ++kk) a2 += ts[kk] * w2[kk * E + t];
  h[(size_t)row * E + t] = a2;
  hb[(size_t)row * E + t] = f2b(a2);
}

// ---------------------------------------------------------------------------
// pairwise-bias collapse: 49 bins per (layer, head)
// ---------------------------------------------------------------------------
__global__ __launch_bounds__(256) void bias_kernel(
    const float* __restrict__ pos, const float* __restrict__ W2d,
    const float* __restrict__ b2d, float* __restrict__ bias49)
{
  int layer = blockIdx.x;
  for (int idx = threadIdx.x; idx < NH * 49; idx += 256) {
    int hh = idx / 49, bin = idx % 49;
    float acc = b2d[layer * NH + hh];
    for (int p = 0; p < PDIM; ++p)
      acc += pos[bin * PDIM + p] * W2d[((size_t)layer * PDIM + p) * NH + hh];
    bias49[(size_t)layer * NH * 49 + hh * 49 + bin] = acc;
  }
}

// ---------------------------------------------------------------------------
// bf16 MFMA GEMM: C = act(A @ Bt^T * scale + bias) (+resid)
// A bf16 [M][K], Bt bf16 [N][K] (pre-transposed). 256 thr = 4 waves (2x2),
// each wave (BM/2)x(BN/2) via 16x16x32 MFMA. LDS rows padded to 40 bf16
// (stride 20 words -> 2-way bank aliasing, free).
// ---------------------------------------------------------------------------
template<int BM, int BN, bool BIAS, bool RELU, bool RESID, bool OUTBF16, bool QKV>
__global__ __launch_bounds__(256) void gemm_mfma(
    const unsigned short* __restrict__ A, const unsigned short* __restrict__ Bt,
    const float* __restrict__ bias, const float* __restrict__ resid,
    float* __restrict__ Cf, unsigned short* __restrict__ Cb, int N, int K)
{
  constexpr int MT = BM / 32, NT = BN / 32;
  __shared__ __align__(16) unsigned short As[BM][40];
  __shared__ __align__(16) unsigned short Bs[BN][40];
  const int tid = threadIdx.x;
  const int wave = tid >> 6, ln = tid & 63;
  const int quad = ln >> 4, l16 = ln & 15;
  const int wm = wave >> 1, wn = wave & 1;
  const int m0 = blockIdx.y * BM, n0 = blockIdx.x * BN;

  floatx4 acc[MT][NT] = {};

  for (int kb = 0; kb < K; kb += 32) {
    __syncthreads();
    #pragma unroll
    for (int it = 0; it < BM / 64; ++it) {
      int c = tid + it * 256;
      int row = c >> 2, cc = (c & 3) * 8;
      *(float4*)&As[row][cc] = *(const float4*)(A + (size_t)(m0 + row) * K + kb + cc);
    }
    #pragma unroll
    for (int it = 0; it < BN / 64; ++it) {
      int c = tid + it * 256;
      int row = c >> 2, cc = (c & 3) * 8;
      *(float4*)&Bs[row][cc] = *(const float4*)(Bt + (size_t)(n0 + row) * K + kb + cc);
    }
    __syncthreads();
    bf16x8 af[MT], bfr[NT];
    #pragma unroll
    for (int i = 0; i < MT; ++i)
      af[i] = *(const bf16x8*)&As[wm * (BM / 2) + i * 16 + l16][quad * 8];
    #pragma unroll
    for (int j = 0; j < NT; ++j)
      bfr[j] = *(const bf16x8*)&Bs[wn * (BN / 2) + j * 16 + l16][quad * 8];
    #pragma unroll
    for (int i = 0; i < MT; ++i)
      #pragma unroll
      for (int j = 0; j < NT; ++j)
        acc[i][j] = __builtin_amdgcn_mfma_f32_16x16x32_bf16(af[i], bfr[j], acc[i][j], 0, 0, 0);
  }

  #pragma unroll
  for (int i = 0; i < MT; ++i)
    #pragma unroll
    for (int j = 0; j < NT; ++j) {
      int col = n0 + wn * (BN / 2) + j * 16 + l16;
      float bv = BIAS ? bias[col] : 0.f;
      float sc = QKV ? (col < 512 ? QSCALE : 1.f) : 1.f;
      #pragma unroll
      for (int r = 0; r < 4; ++r) {
        int rowg = m0 + wm * (BM / 2) + i * 16 + quad * 4 + r;
        float v = acc[i][j][r] * sc + bv;
        if (RELU) v = fmaxf(v, 0.f);
        if (RESID) v += resid[(size_t)rowg * N + col];
        if (OUTBF16) Cb[(size_t)rowg * N + col] = f2b(v);
        else Cf[(size_t)rowg * N + col] = v;
      }
    }
}

// ---------------------------------------------------------------------------
// fp32 flash attention (unchanged structure); reads bf16 qkv [M][1536]
// (q | k | v each 512 wide), writes bf16 o [M][512].
// ---------------------------------------------------------------------------
__global__ __launch_bounds__(256) void attn_kernel(
    const unsigned short* __restrict__ qkv, const float* __restrict__ bias49,
    unsigned short* __restrict__ o)
{
  const int it = blockIdx.x;           // 0..7 query tile
  const int bh = blockIdx.y;           // 0..127
  const int b = bh >> 4, hh = bh & 15;
  const int tid = threadIdx.x;
  const int tx = tid & 15, ty = tid >> 4;
  const int i0 = it * 64;

  __shared__ __align__(16) float Qt[32][68];   // [d][i]
  __shared__ __align__(16) float Kt[32][68];   // [d][j]
  __shared__ __align__(16) float Vs[64][36];   // [j][d]
  __shared__ __align__(16) float Ss[64][76];   // [i][j]
  __shared__ float m_s[64], l_s[64], al_s[64];
  __shared__ float red[64][4];
  __shared__ float bsh[49];

  if (tid < 49) bsh[tid] = bias49[hh * 49 + tid];
  if (tid < 64) { m_s[tid] = -1e30f; l_s[tid] = 0.f; }
  const size_t base = ((size_t)b * Ln) * 1536 + (size_t)hh * HD;
  #pragma unroll
  for (int r2 = 0; r2 < 8; ++r2) {
    int idx = tid + r2 * 256;
    int i = idx >> 5, d = idx & 31;
    Qt[d][i] = b2f(qkv[base + (size_t)(i0 + i) * 1536 + d]);
  }
  float acc[4][2] = {};
  const int row = tid >> 2, seg = tid & 3;

  for (int jt = 0; jt < 8; ++jt) {
    const int j0 = jt * 64;
    __syncthreads();
    #pragma unroll
    for (int r2 = 0; r2 < 8; ++r2) {
      int idx = tid + r2 * 256;
      int i = idx >> 5, d = idx & 31;
      Kt[d][i] = b2f(qkv[base + 512 + (size_t)(j0 + i) * 1536 + d]);
      Vs[i][d] = b2f(qkv[base + 1024 + (size_t)(j0 + i) * 1536 + d]);
    }
    __syncthreads();
    float s[4][4];
    #pragma unroll
    for (int ii = 0; ii < 4; ++ii)
      #pragma unroll
      for (int jj = 0; jj < 4; ++jj) {
        int rel = (j0 + 4 * tx + jj) - (i0 + 4 * ty + ii);
        rel = rel < -PMAX ? -PMAX : (rel > PMAX ? PMAX : rel);
        s[ii][jj] = bsh[rel + PMAX];
      }
    #pragma unroll
    for (int d = 0; d < 32; ++d) {
      float4 a = *(const float4*)&Qt[d][4 * ty];
      float4 bq = *(const float4*)&Kt[d][4 * tx];
      float av4[4] = {a.x, a.y, a.z, a.w};
      float bv4[4] = {bq.x, bq.y, bq.z, bq.w};
      #pragma unroll
      for (int ii = 0; ii < 4; ++ii)
        #pragma unroll
        for (int jj = 0; jj < 4; ++jj)
          s[ii][jj] += av4[ii] * bv4[jj];
    }
    #pragma unroll
    for (int ii = 0; ii < 4; ++ii)
      *(float4*)&Ss[4 * ty + ii][4 * tx] = make_float4(s[ii][0], s[ii][1], s[ii][2], s[ii][3]);
    __syncthreads();
    float mx = -1e30f;
    #pragma unroll
    for (int c = 0; c < 16; ++c) mx = fmaxf(mx, Ss[row][seg * 16 + c]);
    red[row][seg] = mx;
    __syncthreads();
    float tmax = fmaxf(fmaxf(red[row][0], red[row][1]), fmaxf(red[row][2], red[row][3]));
    float mold = m_s[row];
    float mnew = fmaxf(mold, tmax);
    float ps = 0.f;
    #pragma unroll
    for (int c = 0; c < 16; ++c) {
      float p = __expf(Ss[row][seg * 16 + c] - mnew);
      Ss[row][seg * 16 + c] = p;
      ps += p;
    }
    __syncthreads();
    red[row][seg] = ps;
    __syncthreads();
    if (seg == 0) {
      float al = __expf(mold - mnew);
      l_s[row] = l_s[row] * al + (red[row][0] + red[row][1] + red[row][2] + red[row][3]);
      m_s[row] = mnew;
      al_s[row] = al;
    }
    __syncthreads();
    #pragma unroll
    for (int ii = 0; ii < 4; ++ii) {
      float al = al_s[4 * ty + ii];
      acc[ii][0] *= al; acc[ii][1] *= al;
    }
    for (int j4 = 0; j4 < 64; j4 += 4) {
      float2 vv0 = *(const float2*)&Vs[j4 + 0][2 * tx];
      float2 vv1 = *(const float2*)&Vs[j4 + 1][2 * tx];
      float2 vv2 = *(const float2*)&Vs[j4 + 2][2 * tx];
      float2 vv3 = *(const float2*)&Vs[j4 + 3][2 * tx];
      #pragma unroll
      for (int ii = 0; ii < 4; ++ii) {
        float4 p4 = *(const float4*)&Ss[4 * ty + ii][j4];
        acc[ii][0] += p4.x * vv0.x + p4.y * vv1.x + p4.z * vv2.x + p4.w * vv3.x;
        acc[ii][1] += p4.x * vv0.y + p4.y * vv1.y + p4.z * vv2.y + p4.w * vv3.y;
      }
    }
  }
  #pragma unroll
  for (int ii = 0; ii < 4; ++ii) {
    float linv = 1.f / l_s[4 * ty + ii];
    ushort2 ov;
    ov.x = f2b(acc[ii][0] * linv);
    ov.y = f2b(acc[ii][1] * linv);
    *(ushort2*)&o[((size_t)(b * Ln) + i0 + 4 * ty + ii) * 512 + hh * HD + 2 * tx] = ov;
  }
}

// ---------------------------------------------------------------------------
// LayerNorm over E=256; writes h (fp32) and a bf16 mirror with given stride
// ---------------------------------------------------------------------------
__global__ __launch_bounds__(256) void ln_kernel(
    const float* __restrict__ xin, const float* __restrict__ g,
    const float* __restrict__ be, float* __restrict__ hout,
    unsigned short* __restrict__ bout, int bstride)
{
  int row = blockIdx.x, t = threadIdx.x;
  float v = xin[(size_t)row * E + t];
  float s = v;
  #pragma unroll
  for (int off = 32; off > 0; off >>= 1) s += __shfl_down(s, off, 64);
  __shared__ float ws4[4];
  __shared__ float mbc, rbc;
  if ((t & 63) == 0) ws4[t >> 6] = s;
  __syncthreads();
  if (t == 0) mbc = (ws4[0] + ws4[1] + ws4[2] + ws4[3]) * (1.f / E);
  __syncthreads();
  float m = mbc;
  float d = v - m;
  float s2 = d * d;
  #pragma unroll
  for (int off = 32; off > 0; off >>= 1) s2 += __shfl_down(s2, off, 64);
  if ((t & 63) == 0) ws4[t >> 6] = s2;
  __syncthreads();
  if (t == 0) rbc = rsqrtf((ws4[0] + ws4[1] + ws4[2] + ws4[3]) * (1.f / E) + 1e-5f);
  __syncthreads();
  float y = d * rbc * g[t] + be[t];
  hout[(size_t)row * E + t] = y;
  bout[(size_t)row * bstride + t] = f2b(y);
}

// ---------------------------------------------------------------------------
// fp32 tiled GEMM (head only): C = act(A@B + bias)
// ---------------------------------------------------------------------------
template<bool RELU, bool BIAS>
__global__ __launch_bounds__(256) void gemm64f(
    const float* __restrict__ A, const float* __restrict__ B,
    const float* __restrict__ bias, float* __restrict__ C, int N, int K)
{
  __shared__ __align__(16) float As[16][64];
  __shared__ __align__(16) float Bss[16][68];
  const int tid = threadIdx.x;
  const int tx = tid & 15, ty = tid >> 4;
  const int m0 = blockIdx.y * 64, n0 = blockIdx.x * 64;
  const int arow = tid >> 2, acol = (tid & 3) * 4;
  const int brow = tid >> 6, bcol = tid & 63;
  float acc[4][4] = {};
  for (int kb = 0; kb < K; kb += 16) {
    __syncthreads();
    float4 av = *(const float4*)(A + (size_t)(m0 + arow) * K + kb + acol);
    As[acol + 0][arow] = av.x; As[acol + 1][arow] = av.y;
    As[acol + 2][arow] = av.z; As[acol + 3][arow] = av.w;
    #pragma unroll
    for (int kk = 0; kk < 4; ++kk)
      Bss[brow + kk * 4][bcol] = B[(size_t)(kb + brow + kk * 4) * N + n0 + bcol];
    __syncthreads();
    #pragma unroll
    for (int k = 0; k < 16; ++k) {
      float4 a = *(const float4*)&As[k][4 * ty];
      float4 b = *(const float4*)&Bss[k][4 * tx];
      float av4[4] = {a.x, a.y, a.z, a.w};
      float bv4[4] = {b.x, b.y, b.z, b.w};
      #pragma unroll
      for (int ii = 0; ii < 4; ++ii)
        #pragma unroll
        for (int jj = 0; jj < 4; ++jj)
          acc[ii][jj] += av4[ii] * bv4[jj];
    }
  }
  #pragma unroll
  for (int ii = 0; ii < 4; ++ii) {
    size_t row = (size_t)m0 + 4 * ty + ii;
    int col = n0 + 4 * tx;
    float4 vv;
    vv.x = acc[ii][0]; vv.y = acc[ii][1]; vv.z = acc[ii][2]; vv.w = acc[ii][3];
    if (BIAS) {
      float4 bb = *(const float4*)(bias + col);
      vv.x += bb.x; vv.y += bb.y; vv.z += bb.z; vv.w += bb.w;
    }
    if (RELU) {
      vv.x = fmaxf(vv.x, 0.f); vv.y = fmaxf(vv.y, 0.f);
      vv.z = fmaxf(vv.z, 0.f); vv.w = fmaxf(vv.w, 0.f);
    }
    *(float4*)(C + row * N + col) = vv;
  }
}

__global__ __launch_bounds__(256) void final_r_kernel(
    const float* __restrict__ t1, const float* __restrict__ w2,
    const float* __restrict__ b2, float* __restrict__ r)
{
  int row = blockIdx.x, t = threadIdx.x;
  float xv = t1[(size_t)row * E + t];
  float p0 = xv * w2[t * 3 + 0];
  float p1 = xv * w2[t * 3 + 1];
  float p2 = xv * w2[t * 3 + 2];
  #pragma unroll
  for (int off = 32; off > 0; off >>= 1) {
    p0 += __shfl_down(p0, off, 64);
    p1 += __shfl_down(p1, off, 64);
    p2 += __shfl_down(p2, off, 64);
  }
  __shared__ float red[4][3];
  if ((t & 63) == 0) { int w = t >> 6; red[w][0] = p0; red[w][1] = p1; red[w][2] = p2; }
  __syncthreads();
  if (t < 3)
    r[(size_t)row * 3 + t] = red[0][t] + red[1][t] + red[2][t] + red[3][t] + b2[t];
}

__global__ __launch_bounds__(512) void dist_kernel(
    const float* __restrict__ r, float* __restrict__ out)
{
  int bi = blockIdx.x;
  int j = threadIdx.x;
  int b = bi >> 9;
  float x0 = r[(size_t)bi * 3 + 0];
  float y0 = r[(size_t)bi * 3 + 1];
  float z0 = r[(size_t)bi * 3 + 2];
  const float* rj = r + ((size_t)b * Ln + j) * 3;
  float dx = rj[0] - x0, dy = rj[1] - y0, dz = rj[2] - z0;
  out[(size_t)bi * Ln + j] = sqrtf(dx * dx + dy * dy + dz * dz + 1e-12f);
}

// ---------------------------------------------------------------------------
extern "C" void kernel_launch(void* const* d_in, const int* in_sizes, int n_in,
                              void* d_out, int out_size, void* d_ws, size_t ws_size,
                              hipStream_t stream)
{
  const float* z     = (const float*)d_in[0];
  const float* x     = (const float*)d_in[1];
  const float* pos   = (const float*)d_in[2];
  const float* aa    = (const float*)d_in[3];
  const float* ex_w1 = (const float*)d_in[4];
  const float* ex_b1 = (const float*)d_in[5];
  const float* ex_w2 = (const float*)d_in[6];
  const float* ex_b2 = (const float*)d_in[7];
  const float* Wq    = (const float*)d_in[8];
  const float* Wk    = (const float*)d_in[9];
  const float* Wv    = (const float*)d_in[10];
  const float* Wo    = (const float*)d_in[11];
  const float* bo    = (const float*)d_in[12];
  const float* W2d   = (const float*)d_in[13];
  const float* b2d   = (const float*)d_in[14];
  const float* W1    = (const float*)d_in[15];
  const float* b1    = (const float*)d_in[16];
  const float* W2    = (const float*)d_in[17];
  const float* b2    = (const float*)d_in[18];
  const float* g1    = (const float*)d_in[19];
  const float* be1   = (const float*)d_in[20];
  const float* g2    = (const float*)d_in[21];
  const float* be2   = (const float*)d_in[22];
  const float* m3w1  = (const float*)d_in[23];
  const float* m3b1  = (const float*)d_in[24];
  const float* m3w2  = (const float*)d_in[25];
  const float* m3b2  = (const float*)d_in[26];

  float* ws     = (float*)d_ws;
  float* h      = ws;                          // 4096*256
  float* tmp    = h + (size_t)ROWS * E;        // 4096*256
  float* r      = tmp + (size_t)ROWS * E;      // 4096*3
  float* bias49 = r + (size_t)ROWS * 3;        // 8*16*49
  unsigned short* us = (unsigned short*)(bias49 + NL * NH * 49);
  unsigned short* hb   = us;                              // 4096*256
  unsigned short* umb  = hb  + (size_t)ROWS * E;          // 4096*288
  unsigned short* qkvb = umb + (size_t)ROWS * (E + E1D);  // 4096*1536
  unsigned short* ob   = qkvb + (size_t)ROWS * 3 * DM;    // 4096*512
  unsigned short* t1b  = ob  + (size_t)ROWS * DM;         // 4096*1024
  unsigned short* qkvT = t1b + (size_t)ROWS * FF;         // 8*1536*256
  unsigned short* WoT  = qkvT + (size_t)NL * 3 * DM * E;  // 8*256*512
  unsigned short* W1T  = WoT  + (size_t)NL * E * DM;      // 8*1024*288
  unsigned short* W2T  = W1T  + (size_t)NL * FF * (E+E1D);// 8*256*1024
  float* t1f = (float*)t1b;   // head scratch aliases t1b (disjoint lifetime)

  // ---- weight transpose+convert (per call) ----
  transpose_bf16<<<dim3(DM/32, E/32, NL), 256, 0, stream>>>(
      Wq, qkvT + 0,        E, DM, (size_t)E * DM, (size_t)3 * DM * E);
  transpose_bf16<<<dim3(DM/32, E/32, NL), 256, 0, stream>>>(
      Wk, qkvT + DM * E,   E, DM, (size_t)E * DM, (size_t)3 * DM * E);
  transpose_bf16<<<dim3(DM/32, E/32, NL), 256, 0, stream>>>(
      Wv, qkvT + 2 * DM * E, E, DM, (size_t)E * DM, (size_t)3 * DM * E);
  transpose_bf16<<<dim3(E/32, DM/32, NL), 256, 0, stream>>>(
      Wo, WoT, DM, E, (size_t)DM * E, (size_t)DM * E);
  transpose_bf16<<<dim3(FF/32, (E+E1D)/32, NL), 256, 0, stream>>>(
      W1, W1T, E + E1D, FF, (size_t)(E+E1D) * FF, (size_t)(E+E1D) * FF);
  transpose_bf16<<<dim3(E/32, FF/32, NL), 256, 0, stream>>>(
      W2, W2T, FF, E, (size_t)FF * E, (size_t)FF * E);

  embed_kernel<<<ROWS, 256, 0, stream>>>(z, x, aa, ex_w1, ex_b1, ex_w2, ex_b2, h, hb, umb);
  bias_kernel<<<NL, 256, 0, stream>>>(pos, W2d, b2d, bias49);

  for (int i = 0; i < NL; ++i) {
    // fused QKV: N=1536, q-scale on cols<512, bf16 out
    gemm_mfma<128,128,false,false,false,true,true><<<dim3(12, 32), 256, 0, stream>>>(
        hb, qkvT + (size_t)i * 3 * DM * E, nullptr, nullptr, nullptr, qkvb, 3 * DM, E);
    attn_kernel<<<dim3(Ln/64, Bn*NH), 256, 0, stream>>>(
        qkvb, bias49 + (size_t)i * NH * 49, ob);
    // Wo + bias + resid(h) -> tmp fp32
    gemm_mfma<64,64,true,false,true,false,false><<<dim3(E/64, ROWS/64), 256, 0, stream>>>(
        ob, WoT + (size_t)i * DM * E, bo + (size_t)i * E, h, tmp, nullptr, E, DM);
    ln_kernel<<<ROWS, 256, 0, stream>>>(tmp, g1 + (size_t)i * E, be1 + (size_t)i * E, h, umb, E + E1D);
    // FF1 + bias + relu -> bf16 t1b
    gemm_mfma<128,128,true,true,false,true,false><<<dim3(FF/128, ROWS/128), 256, 0, stream>>>(
        umb, W1T + (size_t)i * FF * (E+E1D), b1 + (size_t)i * FF, nullptr, nullptr, t1b, FF, E + E1D);
    // FF2 + bias + resid(h) -> tmp fp32
    gemm_mfma<64,64,true,false,true,false,false><<<dim3(E/64, ROWS/64), 256, 0, stream>>>(
        t1b, W2T + (size_t)i * E * FF, b2 + (size_t)i * E, h, tmp, nullptr, E, FF);
    ln_kernel<<<ROWS, 256, 0, stream>>>(tmp, g2 + (size_t)i * E, be2 + (size_t)i * E, h, hb, E);
  }

  // fp32 head
  gemm64f<true,true><<<dim3(E/64, ROWS/64), 256, 0, stream>>>(h, m3w1, m3b1, t1f, E, E);
  final_r_kernel<<<ROWS, 256, 0, stream>>>(t1f, m3w2, m3b2, r);
  dist_kernel<<<ROWS, 512, 0, stream>>>(r, (float*)d_out);
}

// Round 4
// 986.456 us; speedup vs baseline: 3.0177x; 1.4679x over previous
//
#include <hip/hip_runtime.h>
#include <math.h>

constexpr int Bn = 8, NZ = 16, Ln = 512;
constexpr int E = 256, DM = 512, NH = 16, HD = 32;
constexpr int FF = 1024, NL = 8, E1D = 32, PDIM = 64, PMAX = 24;
constexpr int ROWS = Bn * Ln;                       // 4096
constexpr float QSCALE = 0.04419417382415922f;      // 1/sqrt(512)

typedef __attribute__((ext_vector_type(8))) short bf16x8;
typedef __attribute__((ext_vector_type(4))) float floatx4;

__device__ inline unsigned short f2b(float f) {
  union { float f; unsigned u; } v; v.f = f;
  unsigned r = (v.u + 0x7FFF + ((v.u >> 16) & 1)) >> 16;
  return (unsigned short)r;
}
__device__ inline float b2f(unsigned short u) {
  union { unsigned u; float f; } v; v.u = ((unsigned)u) << 16; return v.f;
}

// ---------------------------------------------------------------------------
// fp32 [l][R][C] -> bf16 [l][C][R] tiled transpose+convert (weights, per call)
// ---------------------------------------------------------------------------
__global__ __launch_bounds__(256) void transpose_bf16(
    const float* __restrict__ src, unsigned short* __restrict__ dst,
    int R, int C, size_t sls, size_t dls)
{
  __shared__ float t[32][33];
  int l = blockIdx.z;
  int c0 = blockIdx.x * 32, r0 = blockIdx.y * 32;
  int tx = threadIdx.x & 31, ty = threadIdx.x >> 5;   // 32 x 8
  const float* s = src + (size_t)l * sls;
  unsigned short* d = dst + (size_t)l * dls;
  #pragma unroll
  for (int i = 0; i < 4; ++i)
    t[ty + i * 8][tx] = s[(size_t)(r0 + ty + i * 8) * C + c0 + tx];
  __syncthreads();
  #pragma unroll
  for (int i = 0; i < 4; ++i)
    d[(size_t)(c0 + ty + i * 8) * R + r0 + tx] = f2b(t[tx][ty + i * 8]);
}

// ---------------------------------------------------------------------------
// embed_x MLP + e_aa gather: writes h (fp32), hb (bf16), umb aa-cols (bf16)
// ---------------------------------------------------------------------------
__global__ __launch_bounds__(256) void embed_kernel(
    const float* __restrict__ z, const float* __restrict__ x,
    const float* __restrict__ aa,
    const float* __restrict__ w1, const float* __restrict__ b1,
    const float* __restrict__ w2, const float* __restrict__ b2,
    float* __restrict__ h, unsigned short* __restrict__ hb,
    unsigned short* __restrict__ umb)
{
  int row = blockIdx.x;
  int b = row >> 9, l = row & (Ln - 1);
  int t = threadIdx.x;
  __shared__ float zs[NZ];
  __shared__ float ts[E];
  __shared__ int am_s;
  if (t < NZ) zs[t] = z[((size_t)b * NZ + t) * Ln + l];
  if (t == 0) {
    const float* xp = x + (size_t)b * 20 * Ln + l;
    int am = 0; float bv = xp[0];
    for (int c = 1; c < 20; ++c) { float vv = xp[(size_t)c * Ln]; if (vv > bv) { bv = vv; am = c; } }
    am_s = am;
  }
  __syncthreads();
  float a1 = b1[t];
  #pragma unroll
  for (int nz = 0; nz < NZ; ++nz) a1 += zs[nz] * w1[nz * E + t];
  ts[t] = fmaxf(a1, 0.f);
  if (t < E1D) umb[(size_t)row * (E + E1D) + E + t] = f2b(aa[am_s * E1D + t]);
  __syncthreads();
  float a2 = b2[t];
  for (int kk = 0; kk < E; ++kk) a2 += ts[kk] * w2[kk * E + t];
  h[(size_t)row * E + t] = a2;
  hb[(size_t)row * E + t] = f2b(a2);
}

// ---------------------------------------------------------------------------
// pairwise-bias collapse: 49 bins per (layer, head)
// ---------------------------------------------------------------------------
__global__ __launch_bounds__(256) void bias_kernel(
    const float* __restrict__ pos, const float* __restrict__ W2d,
    const float* __restrict__ b2d, float* __restrict__ bias49)
{
  int layer = blockIdx.x;
  for (int idx = threadIdx.x; idx < NH * 49; idx += 256) {
    int hh = idx / 49, bin = idx % 49;
    float acc = b2d[layer * NH + hh];
    for (int p = 0; p < PDIM; ++p)
      acc += pos[bin * PDIM + p] * W2d[((size_t)layer * PDIM + p) * NH + hh];
    bias49[(size_t)layer * NH * 49 + hh * 49 + bin] = acc;
  }
}

// ---------------------------------------------------------------------------
// bf16 MFMA GEMM: C = act(A @ Bt^T * scale + bias) (+resid)
// ---------------------------------------------------------------------------
template<int BM, int BN, bool BIAS, bool RELU, bool RESID, bool OUTBF16, bool QKV>
__global__ __launch_bounds__(256) void gemm_mfma(
    const unsigned short* __restrict__ A, const unsigned short* __restrict__ Bt,
    const float* __restrict__ bias, const float* __restrict__ resid,
    float* __restrict__ Cf, unsigned short* __restrict__ Cb, int N, int K)
{
  constexpr int MT = BM / 32, NT = BN / 32;
  __shared__ __align__(16) unsigned short As[BM][40];
  __shared__ __align__(16) unsigned short Bs[BN][40];
  const int tid = threadIdx.x;
  const int wave = tid >> 6, ln = tid & 63;
  const int quad = ln >> 4, l16 = ln & 15;
  const int wm = wave >> 1, wn = wave & 1;
  const int m0 = blockIdx.y * BM, n0 = blockIdx.x * BN;

  floatx4 acc[MT][NT] = {};

  for (int kb = 0; kb < K; kb += 32) {
    __syncthreads();
    #pragma unroll
    for (int it = 0; it < BM / 64; ++it) {
      int c = tid + it * 256;
      int row = c >> 2, cc = (c & 3) * 8;
      *(float4*)&As[row][cc] = *(const float4*)(A + (size_t)(m0 + row) * K + kb + cc);
    }
    #pragma unroll
    for (int it = 0; it < BN / 64; ++it) {
      int c = tid + it * 256;
      int row = c >> 2, cc = (c & 3) * 8;
      *(float4*)&Bs[row][cc] = *(const float4*)(Bt + (size_t)(n0 + row) * K + kb + cc);
    }
    __syncthreads();
    bf16x8 af[MT], bfr[NT];
    #pragma unroll
    for (int i = 0; i < MT; ++i)
      af[i] = *(const bf16x8*)&As[wm * (BM / 2) + i * 16 + l16][quad * 8];
    #pragma unroll
    for (int j = 0; j < NT; ++j)
      bfr[j] = *(const bf16x8*)&Bs[wn * (BN / 2) + j * 16 + l16][quad * 8];
    #pragma unroll
    for (int i = 0; i < MT; ++i)
      #pragma unroll
      for (int j = 0; j < NT; ++j)
        acc[i][j] = __builtin_amdgcn_mfma_f32_16x16x32_bf16(af[i], bfr[j], acc[i][j], 0, 0, 0);
  }

  #pragma unroll
  for (int i = 0; i < MT; ++i)
    #pragma unroll
    for (int j = 0; j < NT; ++j) {
      int col = n0 + wn * (BN / 2) + j * 16 + l16;
      float bv = BIAS ? bias[col] : 0.f;
      float sc = QKV ? (col < 512 ? QSCALE : 1.f) : 1.f;
      #pragma unroll
      for (int r = 0; r < 4; ++r) {
        int rowg = m0 + wm * (BM / 2) + i * 16 + quad * 4 + r;
        float v = acc[i][j][r] * sc + bv;
        if (RELU) v = fmaxf(v, 0.f);
        if (RESID) v += resid[(size_t)rowg * N + col];
        if (OUTBF16) Cb[(size_t)rowg * N + col] = f2b(v);
        else Cf[(size_t)rowg * N + col] = v;
      }
    }
}

// ---------------------------------------------------------------------------
// MFMA flash attention. qkv bf16 [row][1536] (q|k|v, q pre-scaled), o bf16
// [row][512]. Per block: 64 q-rows x one (b,h). 4 waves, 16 q-rows each.
// QK^T: one 16x16x32 MFMA per 16-key tile (K=HD=32, frags direct from
// global/LDS, fp32 accumulate — same precision as fp32 vector path).
// Softmax: fp32 in registers, row-reduce via shfl_xor over the 16-lane group.
// PV: P split hi/lo bf16 (error ~2^-17, protects the 4.5% absmax margin),
// wave-private LDS round-trip for C->A layout, V^T staged in LDS.
// ---------------------------------------------------------------------------
__global__ __launch_bounds__(256) void attn_kernel(
    const unsigned short* __restrict__ qkv, const float* __restrict__ bias49,
    unsigned short* __restrict__ o)
{
  const int i0 = blockIdx.x * 64;
  const int bh = blockIdx.y;
  const int b = bh >> 4, hh = bh & 15;
  const int tid = threadIdx.x;
  const int wave = tid >> 6, ln = tid & 63;
  const int quad = ln >> 4, l16 = ln & 15;

  __shared__ __align__(16) unsigned short Kt[64][40];      // [key][hd], 80B rows
  __shared__ __align__(16) unsigned short Vt[32][72];      // [hd][key], 144B rows
  __shared__ __align__(16) unsigned short Pw[4][2][16][72];// [wave][hi/lo][q][key]
  __shared__ float bsh[49];

  if (tid < 49) bsh[tid] = bias49[hh * 49 + tid];

  const unsigned short* qkvb = qkv + (size_t)b * Ln * 1536;

  // per-wave Q fragment: A[m=q][k=hd], lane m=l16, k=quad*8+j (contiguous)
  const int qrow = i0 + wave * 16 + l16;
  const bf16x8 qf = *(const bf16x8*)(qkvb + (size_t)qrow * 1536 + hh * 32 + quad * 8);

  float m[4], l[4];
  #pragma unroll
  for (int r = 0; r < 4; ++r) { m[r] = -1e30f; l[r] = 0.f; }
  floatx4 acc_o[2] = {};

  // staging index assignments
  const int krow = tid >> 2, kch = (tid & 3) * 8;          // Kt: 64 rows x 4 chunks
  const int vkey = tid & 63, vch = (tid >> 6) * 8;         // Vt: 64 keys x 4 hd-chunks

  for (int jt = 0; jt < 8; ++jt) {
    const int j0 = jt * 64;
    __syncthreads();   // prior iteration's Kt/Vt reads complete (also bsh vis)
    // ---- stage K tile (as-is) and V tile (transposed) ----
    *(float4*)&Kt[krow][kch] =
        *(const float4*)(qkvb + (size_t)(j0 + krow) * 1536 + 512 + hh * 32 + kch);
    bf16x8 vv = *(const bf16x8*)(qkvb + (size_t)(j0 + vkey) * 1536 + 1024 + hh * 32 + vch);
    #pragma unroll
    for (int i = 0; i < 8; ++i) Vt[vch + i][vkey] = (unsigned short)vv[i];
    __syncthreads();

    // ---- S = Q K^T (+bias), 4 tiles of 16 keys ----
    floatx4 s4[4];
    #pragma unroll
    for (int t = 0; t < 4; ++t) {
      bf16x8 kf = *(const bf16x8*)&Kt[16 * t + l16][quad * 8];
      s4[t] = __builtin_amdgcn_mfma_f32_16x16x32_bf16(qf, kf, (floatx4){0.f, 0.f, 0.f, 0.f}, 0, 0, 0);
    }
    const int relmin = j0 - (i0 + 63), relmax = j0 + 63 - i0;
    if (relmin >= PMAX) {
      float bc = bsh[48];
      #pragma unroll
      for (int t = 0; t < 4; ++t)
        #pragma unroll
        for (int r = 0; r < 4; ++r) s4[t][r] += bc;
    } else if (relmax <= -PMAX) {
      float bc = bsh[0];
      #pragma unroll
      for (int t = 0; t < 4; ++t)
        #pragma unroll
        for (int r = 0; r < 4; ++r) s4[t][r] += bc;
    } else {
      const int base_rel = (j0 + l16) - (i0 + wave * 16 + quad * 4);
      #pragma unroll
      for (int t = 0; t < 4; ++t)
        #pragma unroll
        for (int r = 0; r < 4; ++r) {
          int rel = base_rel + 16 * t - r;
          rel = rel < -PMAX ? -PMAX : (rel > PMAX ? PMAX : rel);
          s4[t][r] += bsh[rel + PMAX];
        }
    }

    // ---- online softmax (row r lives in regs across the 16-lane group) ----
    float mloc[4], alpha[4], psum[4];
    #pragma unroll
    for (int r = 0; r < 4; ++r) {
      mloc[r] = fmaxf(fmaxf(s4[0][r], s4[1][r]), fmaxf(s4[2][r], s4[3][r]));
      #pragma unroll
      for (int off = 1; off < 16; off <<= 1)
        mloc[r] = fmaxf(mloc[r], __shfl_xor(mloc[r], off, 64));
      float mnew = fmaxf(m[r], mloc[r]);
      alpha[r] = __expf(m[r] - mnew);
      m[r] = mnew;
      psum[r] = 0.f;
    }
    #pragma unroll
    for (int t = 0; t < 4; ++t)
      #pragma unroll
      for (int r = 0; r < 4; ++r) {
        float p = __expf(s4[t][r] - m[r]);
        s4[t][r] = p;
        psum[r] += p;
      }
    #pragma unroll
    for (int r = 0; r < 4; ++r) {
      #pragma unroll
      for (int off = 1; off < 16; off <<= 1)
        psum[r] += __shfl_xor(psum[r], off, 64);
      l[r] = l[r] * alpha[r] + psum[r];
      acc_o[0][r] *= alpha[r];
      acc_o[1][r] *= alpha[r];
    }

    // ---- P (C-layout) -> LDS hi/lo planes (wave-private, no barrier) ----
    #pragma unroll
    for (int t = 0; t < 4; ++t)
      #pragma unroll
      for (int r = 0; r < 4; ++r) {
        float p = s4[t][r];
        unsigned short hi = f2b(p);
        unsigned short lo = f2b(p - b2f(hi));
        Pw[wave][0][quad * 4 + r][16 * t + l16] = hi;
        Pw[wave][1][quad * 4 + r][16 * t + l16] = lo;
      }

    // ---- O += P @ V  (A-frags b128 from Pw, B-frags b128 from Vt) ----
    #pragma unroll
    for (int kh = 0; kh < 2; ++kh) {
      bf16x8 phi = *(const bf16x8*)&Pw[wave][0][l16][kh * 32 + quad * 8];
      bf16x8 plo = *(const bf16x8*)&Pw[wave][1][l16][kh * 32 + quad * 8];
      #pragma unroll
      for (int nt = 0; nt < 2; ++nt) {
        bf16x8 vf = *(const bf16x8*)&Vt[nt * 16 + l16][kh * 32 + quad * 8];
        acc_o[nt] = __builtin_amdgcn_mfma_f32_16x16x32_bf16(phi, vf, acc_o[nt], 0, 0, 0);
        acc_o[nt] = __builtin_amdgcn_mfma_f32_16x16x32_bf16(plo, vf, acc_o[nt], 0, 0, 0);
      }
    }
  }

  // ---- epilogue: O /= l, write bf16 ----
  #pragma unroll
  for (int r = 0; r < 4; ++r) {
    float inv = 1.f / l[r];
    size_t rowg = (size_t)b * Ln + i0 + wave * 16 + quad * 4 + r;
    #pragma unroll
    for (int nt = 0; nt < 2; ++nt)
      o[rowg * 512 + hh * 32 + nt * 16 + l16] = f2b(acc_o[nt][r] * inv);
  }
}

// ---------------------------------------------------------------------------
// LayerNorm over E=256; writes h (fp32) and a bf16 mirror with given stride
// ---------------------------------------------------------------------------
__global__ __launch_bounds__(256) void ln_kernel(
    const float* __restrict__ xin, const float* __restrict__ g,
    const float* __restrict__ be, float* __restrict__ hout,
    unsigned short* __restrict__ bout, int bstride)
{
  int row = blockIdx.x, t = threadIdx.x;
  float v = xin[(size_t)row * E + t];
  float s = v;
  #pragma unroll
  for (int off = 32; off > 0; off >>= 1) s += __shfl_down(s, off, 64);
  __shared__ float ws4[4];
  __shared__ float mbc, rbc;
  if ((t & 63) == 0) ws4[t >> 6] = s;
  __syncthreads();
  if (t == 0) mbc = (ws4[0] + ws4[1] + ws4[2] + ws4[3]) * (1.f / E);
  __syncthreads();
  float m = mbc;
  float d = v - m;
  float s2 = d * d;
  #pragma unroll
  for (int off = 32; off > 0; off >>= 1) s2 += __shfl_down(s2, off, 64);
  if ((t & 63) == 0) ws4[t >> 6] = s2;
  __syncthreads();
  if (t == 0) rbc = rsqrtf((ws4[0] + ws4[1] + ws4[2] + ws4[3]) * (1.f / E) + 1e-5f);
  __syncthreads();
  float y = d * rbc * g[t] + be[t];
  hout[(size_t)row * E + t] = y;
  bout[(size_t)row * bstride + t] = f2b(y);
}

// ---------------------------------------------------------------------------
// fp32 tiled GEMM (head only): C = act(A@B + bias)
// ---------------------------------------------------------------------------
template<bool RELU, bool BIAS>
__global__ __launch_bounds__(256) void gemm64f(
    const float* __restrict__ A, const float* __restrict__ B,
    const float* __restrict__ bias, float* __restrict__ C, int N, int K)
{
  __shared__ __align__(16) float As[16][64];
  __shared__ __align__(16) float Bss[16][68];
  const int tid = threadIdx.x;
  const int tx = tid & 15, ty = tid >> 4;
  const int m0 = blockIdx.y * 64, n0 = blockIdx.x * 64;
  const int arow = tid >> 2, acol = (tid & 3) * 4;
  const int brow = tid >> 6, bcol = tid & 63;
  float acc[4][4] = {};
  for (int kb = 0; kb < K; kb += 16) {
    __syncthreads();
    float4 av = *(const float4*)(A + (size_t)(m0 + arow) * K + kb + acol);
    As[acol + 0][arow] = av.x; As[acol + 1][arow] = av.y;
    As[acol + 2][arow] = av.z; As[acol + 3][arow] = av.w;
    #pragma unroll
    for (int kk = 0; kk < 4; ++kk)
      Bss[brow + kk * 4][bcol] = B[(size_t)(kb + brow + kk * 4) * N + n0 + bcol];
    __syncthreads();
    #pragma unroll
    for (int k = 0; k < 16; ++k) {
      float4 a = *(const float4*)&As[k][4 * ty];
      float4 b = *(const float4*)&Bss[k][4 * tx];
      float av4[4] = {a.x, a.y, a.z, a.w};
      float bv4[4] = {b.x, b.y, b.z, b.w};
      #pragma unroll
      for (int ii = 0; ii < 4; ++ii)
        #pragma unroll
        for (int jj = 0; jj < 4; ++jj)
          acc[ii][jj] += av4[ii] * bv4[jj];
    }
  }
  #pragma unroll
  for (int ii = 0; ii < 4; ++ii) {
    size_t row = (size_t)m0 + 4 * ty + ii;
    int col = n0 + 4 * tx;
    float4 vv;
    vv.x = acc[ii][0]; vv.y = acc[ii][1]; vv.z = acc[ii][2]; vv.w = acc[ii][3];
    if (BIAS) {
      float4 bb = *(const float4*)(bias + col);
      vv.x += bb.x; vv.y += bb.y; vv.z += bb.z; vv.w += bb.w;
    }
    if (RELU) {
      vv.x = fmaxf(vv.x, 0.f); vv.y = fmaxf(vv.y, 0.f);
      vv.z = fmaxf(vv.z, 0.f); vv.w = fmaxf(vv.w, 0.f);
    }
    *(float4*)(C + row * N + col) = vv;
  }
}

__global__ __launch_bounds__(256) void final_r_kernel(
    const float* __restrict__ t1, const float* __restrict__ w2,
    const float* __restrict__ b2, float* __restrict__ r)
{
  int row = blockIdx.x, t = threadIdx.x;
  float xv = t1[(size_t)row * E + t];
  float p0 = xv * w2[t * 3 + 0];
  float p1 = xv * w2[t * 3 + 1];
  float p2 = xv * w2[t * 3 + 2];
  #pragma unroll
  for (int off = 32; off > 0; off >>= 1) {
    p0 += __shfl_down(p0, off, 64);
    p1 += __shfl_down(p1, off, 64);
    p2 += __shfl_down(p2, off, 64);
  }
  __shared__ float red[4][3];
  if ((t & 63) == 0) { int w = t >> 6; red[w][0] = p0; red[w][1] = p1; red[w][2] = p2; }
  __syncthreads();
  if (t < 3)
    r[(size_t)row * 3 + t] = red[0][t] + red[1][t] + red[2][t] + red[3][t] + b2[t];
}

__global__ __launch_bounds__(512) void dist_kernel(
    const float* __restrict__ r, float* __restrict__ out)
{
  int bi = blockIdx.x;
  int j = threadIdx.x;
  int b = bi >> 9;
  float x0 = r[(size_t)bi * 3 + 0];
  float y0 = r[(size_t)bi * 3 + 1];
  float z0 = r[(size_t)bi * 3 + 2];
  const float* rj = r + ((size_t)b * Ln + j) * 3;
  float dx = rj[0] - x0, dy = rj[1] - y0, dz = rj[2] - z0;
  out[(size_t)bi * Ln + j] = sqrtf(dx * dx + dy * dy + dz * dz + 1e-12f);
}

// ---------------------------------------------------------------------------
extern "C" void kernel_launch(void* const* d_in, const int* in_sizes, int n_in,
                              void* d_out, int out_size, void* d_ws, size_t ws_size,
                              hipStream_t stream)
{
  const float* z     = (const float*)d_in[0];
  const float* x     = (const float*)d_in[1];
  const float* pos   = (const float*)d_in[2];
  const float* aa    = (const float*)d_in[3];
  const float* ex_w1 = (const float*)d_in[4];
  const float* ex_b1 = (const float*)d_in[5];
  const float* ex_w2 = (const float*)d_in[6];
  const float* ex_b2 = (const float*)d_in[7];
  const float* Wq    = (const float*)d_in[8];
  const float* Wk    = (const float*)d_in[9];
  const float* Wv    = (const float*)d_in[10];
  const float* Wo    = (const float*)d_in[11];
  const float* bo    = (const float*)d_in[12];
  const float* W2d   = (const float*)d_in[13];
  const float* b2d   = (const float*)d_in[14];
  const float* W1    = (const float*)d_in[15];
  const float* b1    = (const float*)d_in[16];
  const float* W2    = (const float*)d_in[17];
  const float* b2    = (const float*)d_in[18];
  const float* g1    = (const float*)d_in[19];
  const float* be1   = (const float*)d_in[20];
  const float* g2    = (const float*)d_in[21];
  const float* be2   = (const float*)d_in[22];
  const float* m3w1  = (const float*)d_in[23];
  const float* m3b1  = (const float*)d_in[24];
  const float* m3w2  = (const float*)d_in[25];
  const float* m3b2  = (const float*)d_in[26];

  float* ws     = (float*)d_ws;
  float* h      = ws;                          // 4096*256
  float* tmp    = h + (size_t)ROWS * E;        // 4096*256
  float* r      = tmp + (size_t)ROWS * E;      // 4096*3
  float* bias49 = r + (size_t)ROWS * 3;        // 8*16*49
  unsigned short* us = (unsigned short*)(bias49 + NL * NH * 49);
  unsigned short* hb   = us;                              // 4096*256
  unsigned short* umb  = hb  + (size_t)ROWS * E;          // 4096*288
  unsigned short* qkvb = umb + (size_t)ROWS * (E + E1D);  // 4096*1536
  unsigned short* ob   = qkvb + (size_t)ROWS * 3 * DM;    // 4096*512
  unsigned short* t1b  = ob  + (size_t)ROWS * DM;         // 4096*1024
  unsigned short* qkvT = t1b + (size_t)ROWS * FF;         // 8*1536*256
  unsigned short* WoT  = qkvT + (size_t)NL * 3 * DM * E;  // 8*256*512
  unsigned short* W1T  = WoT  + (size_t)NL * E * DM;      // 8*1024*288
  unsigned short* W2T  = W1T  + (size_t)NL * FF * (E+E1D);// 8*256*1024
  float* t1f = (float*)t1b;   // head scratch aliases t1b (disjoint lifetime)

  // ---- weight transpose+convert (per call) ----
  transpose_bf16<<<dim3(DM/32, E/32, NL), 256, 0, stream>>>(
      Wq, qkvT + 0,        E, DM, (size_t)E * DM, (size_t)3 * DM * E);
  transpose_bf16<<<dim3(DM/32, E/32, NL), 256, 0, stream>>>(
      Wk, qkvT + DM * E,   E, DM, (size_t)E * DM, (size_t)3 * DM * E);
  transpose_bf16<<<dim3(DM/32, E/32, NL), 256, 0, stream>>>(
      Wv, qkvT + 2 * DM * E, E, DM, (size_t)E * DM, (size_t)3 * DM * E);
  transpose_bf16<<<dim3(E/32, DM/32, NL), 256, 0, stream>>>(
      Wo, WoT, DM, E, (size_t)DM * E, (size_t)DM * E);
  transpose_bf16<<<dim3(FF/32, (E+E1D)/32, NL), 256, 0, stream>>>(
      W1, W1T, E + E1D, FF, (size_t)(E+E1D) * FF, (size_t)(E+E1D) * FF);
  transpose_bf16<<<dim3(E/32, FF/32, NL), 256, 0, stream>>>(
      W2, W2T, FF, E, (size_t)FF * E, (size_t)FF * E);

  embed_kernel<<<ROWS, 256, 0, stream>>>(z, x, aa, ex_w1, ex_b1, ex_w2, ex_b2, h, hb, umb);
  bias_kernel<<<NL, 256, 0, stream>>>(pos, W2d, b2d, bias49);

  for (int i = 0; i < NL; ++i) {
    // fused QKV: N=1536, q-scale on cols<512, bf16 out
    gemm_mfma<128,128,false,false,false,true,true><<<dim3(12, 32), 256, 0, stream>>>(
        hb, qkvT + (size_t)i * 3 * DM * E, nullptr, nullptr, nullptr, qkvb, 3 * DM, E);
    attn_kernel<<<dim3(Ln/64, Bn*NH), 256, 0, stream>>>(
        qkvb, bias49 + (size_t)i * NH * 49, ob);
    // Wo + bias + resid(h) -> tmp fp32
    gemm_mfma<64,64,true,false,true,false,false><<<dim3(E/64, ROWS/64), 256, 0, stream>>>(
        ob, WoT + (size_t)i * DM * E, bo + (size_t)i * E, h, tmp, nullptr, E, DM);
    ln_kernel<<<ROWS, 256, 0, stream>>>(tmp, g1 + (size_t)i * E, be1 + (size_t)i * E, h, umb, E + E1D);
    // FF1 + bias + relu -> bf16 t1b
    gemm_mfma<128,128,true,true,false,true,false><<<dim3(FF/128, ROWS/128), 256, 0, stream>>>(
        umb, W1T + (size_t)i * FF * (E+E1D), b1 + (size_t)i * FF, nullptr, nullptr, t1b, FF, E + E1D);
    // FF2 + bias + resid(h) -> tmp fp32
    gemm_mfma<64,64,true,false,true,false,false><<<dim3(E/64, ROWS/64), 256, 0, stream>>>(
        t1b, W2T + (size_t)i * E * FF, b2 + (size_t)i * E, h, tmp, nullptr, E, FF);
    ln_kernel<<<ROWS, 256, 0, stream>>>(tmp, g2 + (size_t)i * E, be2 + (size_t)i * E, h, hb, E);
  }

  // fp32 head
  gemm64f<true,true><<<dim3(E/64, ROWS/64), 256, 0, stream>>>(h, m3w1, m3b1, t1f, E, E);
  final_r_kernel<<<ROWS, 256, 0, stream>>>(t1f, m3w2, m3b2, r);
  dist_kernel<<<ROWS, 512, 0, stream>>>(r, (float*)d_out);
}